// Round 1
// baseline (144.120 us; speedup 1.0000x reference)
//
#include <hip/hip_runtime.h>

#define NUM_BINS 256
#define HH 512
#define WW 512
#define PIX_PER_IMG (HH * WW)          // 262144 = 2^18
#define CH_STRIDE (HH * WW)
#define IMG_STRIDE (3 * HH * WW)
#define BLOCKS_PER_IMG 64
#define THREADS 256

__global__ void zero_hist_kernel(unsigned int* __restrict__ hist) {
    hist[blockIdx.x * blockDim.x + threadIdx.x] = 0u;
}

__global__ __launch_bounds__(THREADS) void hist_kernel(const float* __restrict__ x,
                                                       unsigned int* __restrict__ g_hist) {
    // Per-wave-private LDS histograms: 4 waves * 256 bins * 4B = 4 KB
    __shared__ unsigned int sh[4][NUM_BINS];
    const int wave = threadIdx.x >> 6;

    for (int i = threadIdx.x; i < 4 * NUM_BINS; i += THREADS)
        ((unsigned int*)sh)[i] = 0u;
    __syncthreads();

    const int img = blockIdx.x / BLOCKS_PER_IMG;
    const int blk = blockIdx.x % BLOCKS_PER_IMG;

    const float* base = x + (size_t)img * IMG_STRIDE;
    const float4* r4 = (const float4*)(base);
    const float4* g4 = (const float4*)(base + CH_STRIDE);
    const float4* b4 = (const float4*)(base + 2 * CH_STRIDE);

    const int n4 = PIX_PER_IMG / 4;                 // 65536 float4s per channel
    const int stride = BLOCKS_PER_IMG * THREADS;    // 16384 threads per image
    int tid = blk * THREADS + threadIdx.x;

    for (int i = tid; i < n4; i += stride) {        // 4 iterations
        float4 r = r4[i];
        float4 g = g4[i];
        float4 b = b4[i];

        float y0 = (0.299f * r.x + 0.587f * g.x + 0.114f * b.x) * 255.0f;
        float y1 = (0.299f * r.y + 0.587f * g.y + 0.114f * b.y) * 255.0f;
        float y2 = (0.299f * r.z + 0.587f * g.z + 0.114f * b.z) * 255.0f;
        float y3 = (0.299f * r.w + 0.587f * g.w + 0.114f * b.w) * 255.0f;

        int b0 = (int)rintf(y0);                    // RTE == jnp.round half-to-even
        int b1 = (int)rintf(y1);
        int b2 = (int)rintf(y2);
        int b3 = (int)rintf(y3);
        b0 = min(max(b0, 0), NUM_BINS - 1);
        b1 = min(max(b1, 0), NUM_BINS - 1);
        b2 = min(max(b2, 0), NUM_BINS - 1);
        b3 = min(max(b3, 0), NUM_BINS - 1);

        atomicAdd(&sh[wave][b0], 1u);
        atomicAdd(&sh[wave][b1], 1u);
        atomicAdd(&sh[wave][b2], 1u);
        atomicAdd(&sh[wave][b3], 1u);
    }
    __syncthreads();

    // Reduce the 4 wave-private copies, flush one global atomic per bin
    for (int i = threadIdx.x; i < NUM_BINS; i += THREADS) {
        unsigned int s = sh[0][i] + sh[1][i] + sh[2][i] + sh[3][i];
        if (s) atomicAdd(&g_hist[img * NUM_BINS + i], s);
    }
}

__global__ __launch_bounds__(THREADS) void entropy_kernel(const unsigned int* __restrict__ g_hist,
                                                          float* __restrict__ out) {
    const int img = blockIdx.x;
    const int lane = threadIdx.x & 63;
    const int wave = threadIdx.x >> 6;

    unsigned int c = g_hist[img * NUM_BINS + threadIdx.x];
    // 2^-18 division is exact; matches ref hist/sum exactly
    float p = (float)c * (1.0f / (float)PIX_PER_IMG);
    float v = -p * log2f(p + 1e-8f);

    // wave64 shuffle reduce
    for (int o = 32; o > 0; o >>= 1)
        v += __shfl_down(v, o, 64);

    __shared__ float part[4];
    if (lane == 0) part[wave] = v;
    __syncthreads();
    if (threadIdx.x == 0)
        out[img] = part[0] + part[1] + part[2] + part[3];
}

extern "C" void kernel_launch(void* const* d_in, const int* in_sizes, int n_in,
                              void* d_out, int out_size, void* d_ws, size_t ws_size,
                              hipStream_t stream) {
    const float* x = (const float*)d_in[0];
    float* out = (float*)d_out;
    unsigned int* hist = (unsigned int*)d_ws;

    const int n_img = in_sizes[0] / IMG_STRIDE;     // 32

    zero_hist_kernel<<<n_img, NUM_BINS, 0, stream>>>(hist);
    hist_kernel<<<n_img * BLOCKS_PER_IMG, THREADS, 0, stream>>>(x, hist);
    entropy_kernel<<<n_img, THREADS, 0, stream>>>(hist, out);
}

// Round 2
// 143.904 us; speedup vs baseline: 1.0015x; 1.0015x over previous
//
#include <hip/hip_runtime.h>

#define NUM_BINS 256
#define HH 512
#define WW 512
#define PIX_PER_IMG (HH * WW)          // 262144 = 2^18
#define CH_STRIDE (HH * WW)
#define IMG_STRIDE (3 * HH * WW)
#define BLOCKS_PER_IMG 64
#define THREADS 256

// Kernel 1: per-block partial histograms, no global atomics, no pre-zeroing.
// Each block writes its full 256-bin partial (poison-safe: every slot written).
__global__ __launch_bounds__(THREADS) void hist_kernel(const float* __restrict__ x,
                                                       unsigned int* __restrict__ part) {
    // Per-wave-private LDS histograms: 4 waves * 256 bins * 4B = 4 KB
    __shared__ unsigned int sh[4][NUM_BINS];
    const int wave = threadIdx.x >> 6;

    for (int i = threadIdx.x; i < 4 * NUM_BINS; i += THREADS)
        ((unsigned int*)sh)[i] = 0u;
    __syncthreads();

    const int img = blockIdx.x / BLOCKS_PER_IMG;
    const int blk = blockIdx.x % BLOCKS_PER_IMG;

    const float* base = x + (size_t)img * IMG_STRIDE;
    const float4* r4 = (const float4*)(base);
    const float4* g4 = (const float4*)(base + CH_STRIDE);
    const float4* b4 = (const float4*)(base + 2 * CH_STRIDE);

    const int n4 = PIX_PER_IMG / 4;                 // 65536 float4s per channel
    const int stride = BLOCKS_PER_IMG * THREADS;    // 16384 threads per image
    int tid = blk * THREADS + threadIdx.x;

    for (int i = tid; i < n4; i += stride) {        // 4 iterations
        float4 r = r4[i];
        float4 g = g4[i];
        float4 b = b4[i];

        // Keep EXACT expression order — bit-matched numpy ref (absmax 0.0)
        float y0 = (0.299f * r.x + 0.587f * g.x + 0.114f * b.x) * 255.0f;
        float y1 = (0.299f * r.y + 0.587f * g.y + 0.114f * b.y) * 255.0f;
        float y2 = (0.299f * r.z + 0.587f * g.z + 0.114f * b.z) * 255.0f;
        float y3 = (0.299f * r.w + 0.587f * g.w + 0.114f * b.w) * 255.0f;

        int b0 = (int)rintf(y0);                    // RTE == jnp.round half-to-even
        int b1 = (int)rintf(y1);
        int b2 = (int)rintf(y2);
        int b3 = (int)rintf(y3);
        b0 = min(max(b0, 0), NUM_BINS - 1);
        b1 = min(max(b1, 0), NUM_BINS - 1);
        b2 = min(max(b2, 0), NUM_BINS - 1);
        b3 = min(max(b3, 0), NUM_BINS - 1);

        atomicAdd(&sh[wave][b0], 1u);
        atomicAdd(&sh[wave][b1], 1u);
        atomicAdd(&sh[wave][b2], 1u);
        atomicAdd(&sh[wave][b3], 1u);
    }
    __syncthreads();

    // Flush per-block partial (non-atomic, coalesced: 1 KB/block)
    unsigned int* dst = part + (size_t)blockIdx.x * NUM_BINS;
    for (int i = threadIdx.x; i < NUM_BINS; i += THREADS)
        dst[i] = sh[0][i] + sh[1][i] + sh[2][i] + sh[3][i];
}

// Kernel 2: sum 64 partials per image per bin, then entropy reduce.
__global__ __launch_bounds__(THREADS) void entropy_kernel(const unsigned int* __restrict__ part,
                                                          float* __restrict__ out) {
    const int img = blockIdx.x;
    const int lane = threadIdx.x & 63;
    const int wave = threadIdx.x >> 6;

    const unsigned int* p = part + (size_t)img * BLOCKS_PER_IMG * NUM_BINS;
    unsigned int c = 0;
    #pragma unroll 8
    for (int b = 0; b < BLOCKS_PER_IMG; ++b)
        c += p[b * NUM_BINS + threadIdx.x];         // coalesced across lanes

    // 2^-18 division exact; matches ref hist/sum exactly
    float prob = (float)c * (1.0f / (float)PIX_PER_IMG);
    float v = -prob * log2f(prob + 1e-8f);

    for (int o = 32; o > 0; o >>= 1)
        v += __shfl_down(v, o, 64);

    __shared__ float pw[4];
    if (lane == 0) pw[wave] = v;
    __syncthreads();
    if (threadIdx.x == 0)
        out[img] = pw[0] + pw[1] + pw[2] + pw[3];
}

extern "C" void kernel_launch(void* const* d_in, const int* in_sizes, int n_in,
                              void* d_out, int out_size, void* d_ws, size_t ws_size,
                              hipStream_t stream) {
    const float* x = (const float*)d_in[0];
    float* out = (float*)d_out;
    unsigned int* part = (unsigned int*)d_ws;       // 2048 * 256 * 4B = 2 MB

    const int n_img = in_sizes[0] / IMG_STRIDE;     // 32

    hist_kernel<<<n_img * BLOCKS_PER_IMG, THREADS, 0, stream>>>(x, part);
    entropy_kernel<<<n_img, THREADS, 0, stream>>>(part, out);
}